// Round 1
// baseline (22874.454 us; speedup 1.0000x reference)
//
#include <hip/hip_runtime.h>
#include <cstdint>
#include <cstddef>

#define C1_THREADS 896

// ---------------- weight reorders ----------------
// conv1_w (256,64,9,9) -> w1r[tap][ci][co]  (81,64,256)
__global__ void reorder_w1_kernel(const float* __restrict__ w, float* __restrict__ r) {
    int idx = blockIdx.x * 256 + threadIdx.x;
    if (idx >= 81 * 64 * 256) return;
    int co = idx & 255;
    int ci = (idx >> 8) & 63;
    int tap = idx >> 14;
    r[idx] = w[(co * 64 + ci) * 81 + tap];
}

// pc_w (48,256,8,8) -> pcwr[tap][ci][co]  (64,256,48)
__global__ void reorder_pcw_kernel(const float* __restrict__ w, float* __restrict__ r) {
    int idx = blockIdx.x * 256 + threadIdx.x;
    if (idx >= 64 * 256 * 48) return;
    int co = idx % 48;
    int ci = (idx / 48) % 256;
    int tap = idx / (48 * 256);
    r[idx] = w[(co * 256 + ci) * 64 + tap];
}

// ---------------- conv1 + bias + relu ----------------
// x: (B,64,22,22) NCHW ; out: NHWC-per-image  c1o[il][s=196][co=256]
// block = 1 image, 896 threads: ls = co-slot (64), pg = output row (14)
// thread computes 4 co (ls, ls+64, ls+128, ls+192) x 14 columns of row pg
__global__ __launch_bounds__(C1_THREADS) void conv1_kernel(
    const float* __restrict__ x, const float* __restrict__ w1r,
    const float* __restrict__ b1, float* __restrict__ c1o,
    int c0) {
    __shared__ float Xs[8][484];   // 8 ci x 22*22
    __shared__ float Wl[8][256];   // 8 ci x 256 co (one tap)
    const int t  = threadIdx.x;
    const int ls = t & 63;
    const int pg = t >> 6;         // 0..13 = output row
    const int il = blockIdx.x;     // local image
    const int bg = c0 + il;        // global image

    float a0[14], a1[14], a2[14], a3[14];
#pragma unroll
    for (int i = 0; i < 14; ++i) { a0[i] = 0.f; a1[i] = 0.f; a2[i] = 0.f; a3[i] = 0.f; }

    for (int cc = 0; cc < 8; ++cc) {          // ci chunks of 8
        __syncthreads();                      // protect Xs from previous chunk readers
        for (int i = t; i < 8 * 484; i += C1_THREADS) {
            int ci = i / 484;
            int s  = i - ci * 484;
            Xs[ci][s] = x[((size_t)bg * 64 + cc * 8 + ci) * 484 + s];
        }
        for (int tap = 0; tap < 81; ++tap) {
            __syncthreads();                  // Xs staged / Wl free
            for (int i = t; i < 8 * 256; i += C1_THREADS) {
                int ci = i >> 8;
                int co = i & 255;
                Wl[ci][co] = w1r[((size_t)tap * 64 + cc * 8 + ci) * 256 + co];
            }
            __syncthreads();
            const int kh = tap / 9, kw = tap - kh * 9;
            const float* xb = &Xs[0][(pg + kh) * 22 + kw];
#pragma unroll
            for (int ci = 0; ci < 8; ++ci) {
                const float w0 = Wl[ci][ls];
                const float w1v = Wl[ci][ls + 64];
                const float w2 = Wl[ci][ls + 128];
                const float w3 = Wl[ci][ls + 192];
                const float* xr = xb + ci * 484;
#pragma unroll
                for (int i = 0; i < 14; ++i) {
                    const float xv = xr[i];
                    a0[i] = fmaf(xv, w0, a0[i]);
                    a1[i] = fmaf(xv, w1v, a1[i]);
                    a2[i] = fmaf(xv, w2, a2[i]);
                    a3[i] = fmaf(xv, w3, a3[i]);
                }
            }
        }
    }
    const float bb0 = b1[ls], bb1 = b1[ls + 64], bb2 = b1[ls + 128], bb3 = b1[ls + 192];
#pragma unroll
    for (int i = 0; i < 14; ++i) {
        size_t rowo = ((size_t)il * 196 + pg * 14 + i) * 256;
        c1o[rowo + ls      ] = fmaxf(a0[i] + bb0, 0.f);
        c1o[rowo + ls + 64 ] = fmaxf(a1[i] + bb1, 0.f);
        c1o[rowo + ls + 128] = fmaxf(a2[i] + bb2, 0.f);
        c1o[rowo + ls + 192] = fmaxf(a3[i] + bb3, 0.f);
    }
}

// ---------------- primary caps conv (stride 2) + bias ----------------
// in: c1o NHWC [il][196][256] ; out: pco[il][co*16+pos] (48 co, 16 pos)
__global__ __launch_bounds__(256) void pc_kernel(
    const float* __restrict__ c1o, const float* __restrict__ pcwr,
    const float* __restrict__ pcb, float* __restrict__ pco) {
    __shared__ float Xs[64][197];
    __shared__ float Wl[64][48];
    const int t = threadIdx.x;
    const int il = blockIdx.x;
    const int coslot = t >> 4;
    const int pos = t & 15;
    const int oh = pos >> 2, ow = pos & 3;
    float acc0 = 0.f, acc1 = 0.f, acc2 = 0.f;
    for (int cc = 0; cc < 4; ++cc) {
        __syncthreads();
        for (int i = t; i < 64 * 196; i += 256) {
            int ci = i & 63;
            int s  = i >> 6;
            Xs[ci][s] = c1o[((size_t)il * 196 + s) * 256 + cc * 64 + ci];
        }
        for (int tap = 0; tap < 64; ++tap) {
            __syncthreads();
            for (int i = t; i < 64 * 48; i += 256) {
                int ci = i / 48;
                int co = i - ci * 48;
                Wl[ci][co] = pcwr[((size_t)tap * 256 + cc * 64 + ci) * 48 + co];
            }
            __syncthreads();
            const int kh = tap >> 3, kw = tap & 7;
            const int pixb = (2 * oh + kh) * 14 + 2 * ow + kw;
#pragma unroll
            for (int ci = 0; ci < 64; ++ci) {
                const float xv = Xs[ci][pixb];
                acc0 = fmaf(xv, Wl[ci][coslot], acc0);
                acc1 = fmaf(xv, Wl[ci][coslot + 16], acc1);
                acc2 = fmaf(xv, Wl[ci][coslot + 32], acc2);
            }
        }
    }
    pco[(size_t)il * 768 + (coslot)      * 16 + pos] = acc0 + pcb[coslot];
    pco[(size_t)il * 768 + (coslot + 16) * 16 + pos] = acc1 + pcb[coslot + 16];
    pco[(size_t)il * 768 + (coslot + 32) * 16 + pos] = acc2 + pcb[coslot + 32];
}

// ---------------- capsule squash + u_hat + routing + logits + mask ----------------
__global__ __launch_bounds__(64) void caps_kernel(
    const float* __restrict__ pco, const float* __restrict__ Wd,
    float* __restrict__ logits_out, float* __restrict__ hbuf, int c0) {
    __shared__ float u_s[96][8];
    __shared__ float uh[2][96][16];
    __shared__ float vv[2][16];
    __shared__ float cc2[2][96];
    __shared__ float lg_s[2];
    const int t = threadIdx.x;
    const int il = blockIdx.x;

    // u = squash(pc rows of 8)
    for (int cap = t; cap < 96; cap += 64) {
        float xr[8];
        float n2 = 0.f;
#pragma unroll
        for (int k = 0; k < 8; ++k) {
            xr[k] = pco[(size_t)il * 768 + cap * 8 + k];
            n2 = fmaf(xr[k], xr[k], n2);
        }
        float nr = sqrtf(n2);
        float sc = tanhf(nr) / (nr + 1e-8f);
#pragma unroll
        for (int k = 0; k < 8; ++k) u_s[cap][k] = xr[k] * sc;
    }
    __syncthreads();
    // u_hat[o][i][d] = sum_k Wd[o][i][d][k] * u[i][k]
    for (int j = t; j < 3072; j += 64) {
        int d = j & 15;
        int oi = j >> 4;           // o*96 + i
        int i = oi % 96;
        int o = oi / 96;
        float acc = 0.f;
#pragma unroll
        for (int k = 0; k < 8; ++k)
            acc = fmaf(Wd[(size_t)j * 8 + k], u_s[i][k], acc);
        uh[o][i][d] = acc;
    }
    __syncthreads();
    const int o = t >> 4, d = t & 15;
    // routing iteration 1: c = 0.5 ; v0 = squash(sum_i 0.5*u_hat)
    if (t < 32) {
        float s = 0.f;
        for (int i = 0; i < 96; ++i) s += 0.5f * uh[o][i][d];
        float n2 = s * s;
        n2 += __shfl_xor(n2, 1); n2 += __shfl_xor(n2, 2);
        n2 += __shfl_xor(n2, 4); n2 += __shfl_xor(n2, 8);
        float nr = sqrtf(n2);
        vv[o][d] = tanhf(nr) * s / (nr + 1e-8f);
    }
    __syncthreads();
    // b[o][i] = sum_d uh*v0
    for (int j = t; j < 192; j += 64) {
        int oo = j / 96, ii = j - oo * 96;
        float bsum = 0.f;
#pragma unroll
        for (int dd = 0; dd < 16; ++dd)
            bsum = fmaf(uh[oo][ii][dd], vv[oo][dd], bsum);
        cc2[oo][ii] = bsum;
    }
    __syncthreads();
    // softmax over o
    for (int ii = t; ii < 96; ii += 64) {
        float b0 = cc2[0][ii], b1v = cc2[1][ii];
        float m = fmaxf(b0, b1v);
        float e0 = expf(b0 - m), e1 = expf(b1v - m);
        float inv = 1.f / (e0 + e1);
        cc2[0][ii] = e0 * inv;
        cc2[1][ii] = e1 * inv;
    }
    __syncthreads();
    // final v, logits
    if (t < 32) {
        float s = 0.f;
        for (int i = 0; i < 96; ++i) s = fmaf(cc2[o][i], uh[o][i][d], s);
        float n2 = s * s;
        n2 += __shfl_xor(n2, 1); n2 += __shfl_xor(n2, 2);
        n2 += __shfl_xor(n2, 4); n2 += __shfl_xor(n2, 8);
        float nr = sqrtf(n2);
        float v = tanhf(nr) * s / (nr + 1e-8f);
        float n2v = v * v;
        n2v += __shfl_xor(n2v, 1); n2v += __shfl_xor(n2v, 2);
        n2v += __shfl_xor(n2v, 4); n2v += __shfl_xor(n2v, 8);
        vv[o][d] = v;
        if (d == 0) {
            float lg = sqrtf(n2v);
            lg_s[o] = lg;
            logits_out[(size_t)(c0 + il) * 2 + o] = lg;
        }
    }
    __syncthreads();
    if (t < 32) {
        int ostar = (lg_s[1] > lg_s[0]) ? 1 : 0;
        hbuf[(size_t)il * 32 + t] = (o == ostar) ? vv[o][d] : 0.f;
    }
}

// ---------------- decoder FC: out = act(in @ W^T + b) ----------------
// act: 0 = relu, 1 = sigmoid
__global__ __launch_bounds__(256) void fc_kernel(
    const float* __restrict__ in, const float* __restrict__ W,
    const float* __restrict__ bias, float* __restrict__ out,
    int M, int N, int K, int act) {
    __shared__ float As[64][33];
    __shared__ float Bs[64][33];
    const int t = threadIdx.x;
    const int m0 = blockIdx.x * 64, n0 = blockIdx.y * 64;
    const int tn = t & 15, tm = t >> 4;
    float acc[4][4];
#pragma unroll
    for (int i = 0; i < 4; ++i)
#pragma unroll
        for (int j = 0; j < 4; ++j) acc[i][j] = 0.f;
    const int rr = t >> 2, c8 = (t & 3) * 8;
    for (int kc = 0; kc < K; kc += 32) {
        __syncthreads();
        const int mrow = m0 + rr;
#pragma unroll
        for (int q = 0; q < 8; ++q) {
            As[rr][c8 + q] = (mrow < M) ? in[(size_t)mrow * K + kc + c8 + q] : 0.f;
            Bs[rr][c8 + q] = W[(size_t)(n0 + rr) * K + kc + c8 + q];
        }
        __syncthreads();
#pragma unroll
        for (int k = 0; k < 32; ++k) {
            float av[4], bv[4];
#pragma unroll
            for (int i = 0; i < 4; ++i) av[i] = As[tm * 4 + i][k];
#pragma unroll
            for (int j = 0; j < 4; ++j) bv[j] = Bs[tn * 4 + j][k];
#pragma unroll
            for (int i = 0; i < 4; ++i)
#pragma unroll
                for (int j = 0; j < 4; ++j) acc[i][j] = fmaf(av[i], bv[j], acc[i][j]);
        }
    }
#pragma unroll
    for (int i = 0; i < 4; ++i) {
        int m = m0 + tm * 4 + i;
        if (m < M) {
#pragma unroll
            for (int j = 0; j < 4; ++j) {
                int nn = n0 + tn * 4 + j;
                float v = acc[i][j] + bias[nn];
                if (act == 0) v = fmaxf(v, 0.f);
                else v = 1.f / (1.f + expf(-v));
                out[(size_t)m * N + nn] = v;
            }
        }
    }
}

// ---------------- host ----------------
extern "C" void kernel_launch(void* const* d_in, const int* in_sizes, int n_in,
                              void* d_out, int out_size, void* d_ws, size_t ws_size,
                              hipStream_t stream) {
    const float* x    = (const float*)d_in[0];
    const float* w1   = (const float*)d_in[1];
    const float* b1   = (const float*)d_in[2];
    const float* pcw  = (const float*)d_in[3];
    const float* pcb  = (const float*)d_in[4];
    const float* Wd   = (const float*)d_in[5];
    const float* dw1  = (const float*)d_in[6];
    const float* db1  = (const float*)d_in[7];
    const float* dw2  = (const float*)d_in[8];
    const float* db2  = (const float*)d_in[9];
    const float* dw3  = (const float*)d_in[10];
    const float* db3  = (const float*)d_in[11];
    float* out = (float*)d_out;

    const int B = 2048;
    float* ws = (float*)d_ws;
    float* w1r  = ws;                               // 81*64*256   = 1,327,104 floats
    float* pcwr = w1r + 81 * 64 * 256;              // 64*256*48   =   786,432 floats
    float* dyn  = pcwr + 64 * 256 * 48;

    const long long base_floats = 1327104LL + 786432LL;
    const long long per_img = 50176 + 768 + 32 + 512 + 1024;   // 52,512 floats/img
    long long avail = (long long)(ws_size / 4) - base_floats;
    int CH;
    if (avail < per_img) CH = 1;
    else CH = (int)(avail / per_img);
    if (CH > B) CH = B;

    reorder_w1_kernel<<<(81 * 64 * 256 + 255) / 256, 256, 0, stream>>>(w1, w1r);
    reorder_pcw_kernel<<<(64 * 256 * 48 + 255) / 256, 256, 0, stream>>>(pcw, pcwr);

    float* c1o  = dyn;
    float* pco  = c1o  + (size_t)CH * 50176;
    float* hbuf = pco  + (size_t)CH * 768;
    float* h1   = hbuf + (size_t)CH * 32;
    float* h2   = h1   + (size_t)CH * 512;

    for (int c0 = 0; c0 < B; c0 += CH) {
        int n = B - c0; if (n > CH) n = CH;
        conv1_kernel<<<n, C1_THREADS, 0, stream>>>(x, w1r, b1, c1o, c0);
        pc_kernel<<<n, 256, 0, stream>>>(c1o, pcwr, pcb, pco);
        caps_kernel<<<n, 64, 0, stream>>>(pco, Wd, out, hbuf, c0);
        fc_kernel<<<dim3((n + 63) / 64, 8),  256, 0, stream>>>(hbuf, dw1, db1, h1, n, 512, 32, 0);
        fc_kernel<<<dim3((n + 63) / 64, 16), 256, 0, stream>>>(h1,   dw2, db2, h2, n, 1024, 512, 0);
        fc_kernel<<<dim3((n + 63) / 64, 4),  256, 0, stream>>>(h2,   dw3, db3, out + 4096 + (size_t)c0 * 256, n, 256, 1024, 1);
    }
}

// Round 4
// 9758.311 us; speedup vs baseline: 2.3441x; 2.3441x over previous
//
#include <hip/hip_runtime.h>
#include <cstdint>
#include <cstddef>

typedef short short8 __attribute__((ext_vector_type(8)));
typedef short short4v __attribute__((ext_vector_type(4)));
typedef float f32x16 __attribute__((ext_vector_type(16)));

__device__ inline unsigned short bf16_rne(float x) {
    unsigned u = __float_as_uint(x);
    unsigned r = u + 0x7FFFu + ((u >> 16) & 1u);
    return (unsigned short)(r >> 16);
}
__device__ inline float bf16_to_f(unsigned short h) {
    return __uint_as_float(((unsigned)h) << 16);
}

// ---------------- weight reorders ----------------
// conv1_w (256,64,9,9) -> MFMA-fragment-order split-bf16 planes:
// wf[(ksg*8 + nc)*1024 u16]: [0..511]=hi frag, [512..1023]=lo frag
// ksg = cc*81 + tap (cc = 16-ci chunk) ; ci = cc*16 + (l>>5)*8 + j ; co = nc*32 + (l&31)
__global__ void reorder_wf_kernel(const float* __restrict__ w, unsigned short* __restrict__ wf) {
    int idx = blockIdx.x * 256 + threadIdx.x;      // over 324*8*64*8 = 1,327,104
    if (idx >= 324 * 8 * 64 * 8) return;
    int j   = idx & 7;
    int l   = (idx >> 3) & 63;
    int nc  = (idx >> 9) & 7;
    int ksg = idx >> 12;                           // 0..323
    int cc  = ksg / 81;
    int tap = ksg - cc * 81;
    int ci  = cc * 16 + ((l >> 5) << 3) + j;
    int co  = nc * 32 + (l & 31);
    float v = w[(co * 64 + ci) * 81 + tap];
    unsigned short hi = bf16_rne(v);
    unsigned short lo = bf16_rne(v - bf16_to_f(hi));
    size_t base = ((size_t)(ksg * 8 + nc)) * 1024;
    wf[base + l * 8 + j]       = hi;
    wf[base + 512 + l * 8 + j] = lo;
}

// pc_w (48,256,8,8) -> pcwr[tap][ci][co]  (64,256,48)
__global__ void reorder_pcw_kernel(const float* __restrict__ w, float* __restrict__ r) {
    int idx = blockIdx.x * 256 + threadIdx.x;
    if (idx >= 64 * 256 * 48) return;
    int co = idx % 48;
    int ci = (idx / 48) % 256;
    int tap = idx / (48 * 256);
    r[idx] = w[(co * 256 + ci) * 64 + tap];
}

// ---------------- conv1 via split-bf16 MFMA ----------------
// per image: M=196px (7 tiles of 32, padded), N=256co, K=5184 (4 ci-chunks x 81 taps x 16)
// block = 256 thr = 4 waves = 4 n-cols of 32 co ; grid = n_images * 2 (co halves)
// LDS: Xs[484][36] u16 static = 34,848 B : per spatial row [hi ci 0..15][lo ci 0..15][pad 4]
#define RS 36

__global__ __launch_bounds__(256, 2) void conv1_mfma_kernel(
    const float* __restrict__ x, const unsigned short* __restrict__ wf,
    const float* __restrict__ b1, float* __restrict__ c1o, int c0)
{
    __shared__ unsigned short Xs[484 * RS];
    const int t  = threadIdx.x;
    const int l  = t & 63;
    const int w  = t >> 6;            // wave 0..3
    const int il = blockIdx.x >> 1;
    const int nb = blockIdx.x & 1;
    const int bg = c0 + il;
    const int ncol = nb * 4 + w;
    const int lane31 = l & 31;
    const int kg = l >> 5;
    const int co = ncol * 32 + lane31;
    const float bias = b1[co];

    int am[7];
#pragma unroll
    for (int mt = 0; mt < 7; ++mt) {
        int p  = mt * 32 + lane31;
        int pp = (p < 196) ? p : 0;      // clamp pad rows into valid LDS
        int oh = pp / 14, ow = pp - oh * 14;
        am[mt] = (oh * 22 + ow) * RS + kg * 8;
    }
    const char* wfb = (const char*)wf;
    const int boff = ncol * 2048 + l * 16;

    f32x16 acc[7];
#pragma unroll
    for (int mt = 0; mt < 7; ++mt) acc[mt] = (f32x16)(0.f);

    for (int cc = 0; cc < 4; ++cc) {
        __syncthreads();
        // stage 16-ci chunk: fp32 -> hi/lo bf16 halves of each spatial row
        for (int i = t; i < 16 * 121; i += 256) {
            int ci = i / 121;
            int sq = i - ci * 121;
            const float4 v = *(const float4*)(x + ((size_t)bg * 64 + cc * 16 + ci) * 484 + sq * 4);
#pragma unroll
            for (int e = 0; e < 4; ++e) {
                float xv = ((const float*)&v)[e];
                unsigned short hi = bf16_rne(xv);
                unsigned short lo = bf16_rne(xv - bf16_to_f(hi));
                int s = sq * 4 + e;
                Xs[s * RS + ci]      = hi;
                Xs[s * RS + 16 + ci] = lo;
            }
        }
        __syncthreads();

        const int ksgb = cc * 81;
        short8 bh0 = *(const short8*)(wfb + (size_t)ksgb * 16384 + boff);
        short8 bl0 = *(const short8*)(wfb + (size_t)ksgb * 16384 + 1024 + boff);

        for (int tap = 0; tap < 81; ++tap) {
            // prefetch next tap's B frags (L2-resident)
            int kn = ksgb + tap + 1; if (kn > 323) kn = 323;
            short8 bh1 = *(const short8*)(wfb + (size_t)kn * 16384 + boff);
            short8 bl1 = *(const short8*)(wfb + (size_t)kn * 16384 + 1024 + boff);

            const int kh = tap / 9, kw = tap - kh * 9;
            const int toff = (kh * 22 + kw) * RS;
#pragma unroll
            for (int mt = 0; mt < 7; ++mt) {
                const int a = am[mt] + toff;
                short4v h0 = *(const short4v*)(Xs + a);
                short4v h1 = *(const short4v*)(Xs + a + 4);
                short4v q0 = *(const short4v*)(Xs + a + 16);
                short4v q1 = *(const short4v*)(Xs + a + 20);
                short8 Ah = __builtin_shufflevector(h0, h1, 0, 1, 2, 3, 4, 5, 6, 7);
                short8 Al = __builtin_shufflevector(q0, q1, 0, 1, 2, 3, 4, 5, 6, 7);
                acc[mt] = __builtin_amdgcn_mfma_f32_32x32x16_bf16(Ah, bh0, acc[mt], 0, 0, 0);
                acc[mt] = __builtin_amdgcn_mfma_f32_32x32x16_bf16(Ah, bl0, acc[mt], 0, 0, 0);
                acc[mt] = __builtin_amdgcn_mfma_f32_32x32x16_bf16(Al, bh0, acc[mt], 0, 0, 0);
                acc[mt] = __builtin_amdgcn_mfma_f32_32x32x16_bf16(Al, bl0, acc[mt], 0, 0, 0);
            }
            bh0 = bh1; bl0 = bl1;
        }
    }

    // epilogue: bias + relu, NHWC store (C/D: col=lane&31, row=(r&3)+8*(r>>2)+4*(lane>>5))
#pragma unroll
    for (int mt = 0; mt < 7; ++mt) {
#pragma unroll
        for (int r = 0; r < 16; ++r) {
            int p = mt * 32 + (r & 3) + ((r >> 2) << 3) + kg * 4;
            if (p < 196) {
                float v = acc[mt][r] + bias;
                c1o[((size_t)il * 196 + p) * 256 + co] = fmaxf(v, 0.f);
            }
        }
    }
}

// ---------------- primary caps conv (stride 2) + bias ----------------
__global__ __launch_bounds__(256) void pc_kernel(
    const float* __restrict__ c1o, const float* __restrict__ pcwr,
    const float* __restrict__ pcb, float* __restrict__ pco) {
    __shared__ float Xs[64][197];
    __shared__ float Wl[64][48];
    const int t = threadIdx.x;
    const int il = blockIdx.x;
    const int coslot = t >> 4;
    const int pos = t & 15;
    const int oh = pos >> 2, ow = pos & 3;
    float acc0 = 0.f, acc1 = 0.f, acc2 = 0.f;
    for (int cc = 0; cc < 4; ++cc) {
        __syncthreads();
        for (int i = t; i < 64 * 196; i += 256) {
            int ci = i & 63;
            int s  = i >> 6;
            Xs[ci][s] = c1o[((size_t)il * 196 + s) * 256 + cc * 64 + ci];
        }
        for (int tap = 0; tap < 64; ++tap) {
            __syncthreads();
            for (int i = t; i < 64 * 48; i += 256) {
                int ci = i / 48;
                int co = i - ci * 48;
                Wl[ci][co] = pcwr[((size_t)tap * 256 + cc * 64 + ci) * 48 + co];
            }
            __syncthreads();
            const int kh = tap >> 3, kw = tap & 7;
            const int pixb = (2 * oh + kh) * 14 + 2 * ow + kw;
#pragma unroll
            for (int ci = 0; ci < 64; ++ci) {
                const float xv = Xs[ci][pixb];
                acc0 = fmaf(xv, Wl[ci][coslot], acc0);
                acc1 = fmaf(xv, Wl[ci][coslot + 16], acc1);
                acc2 = fmaf(xv, Wl[ci][coslot + 32], acc2);
            }
        }
    }
    pco[(size_t)il * 768 + (coslot)      * 16 + pos] = acc0 + pcb[coslot];
    pco[(size_t)il * 768 + (coslot + 16) * 16 + pos] = acc1 + pcb[coslot + 16];
    pco[(size_t)il * 768 + (coslot + 32) * 16 + pos] = acc2 + pcb[coslot + 32];
}

// ---------------- capsule squash + u_hat + routing + logits + mask ----------------
__global__ __launch_bounds__(64) void caps_kernel(
    const float* __restrict__ pco, const float* __restrict__ Wd,
    float* __restrict__ logits_out, float* __restrict__ hbuf, int c0) {
    __shared__ float u_s[96][8];
    __shared__ float uh[2][96][16];
    __shared__ float vv[2][16];
    __shared__ float cc2[2][96];
    __shared__ float lg_s[2];
    const int t = threadIdx.x;
    const int il = blockIdx.x;

    for (int cap = t; cap < 96; cap += 64) {
        float xr[8];
        float n2 = 0.f;
#pragma unroll
        for (int k = 0; k < 8; ++k) {
            xr[k] = pco[(size_t)il * 768 + cap * 8 + k];
            n2 = fmaf(xr[k], xr[k], n2);
        }
        float nr = sqrtf(n2);
        float sc = tanhf(nr) / (nr + 1e-8f);
#pragma unroll
        for (int k = 0; k < 8; ++k) u_s[cap][k] = xr[k] * sc;
    }
    __syncthreads();
    // u_hat[o][i][d] = sum_k Wd[o][i][d][k] * u[i][k]  (j = (o*96+i)*16 + d)
    for (int j = t; j < 3072; j += 64) {
        int d = j & 15;
        int oi = j >> 4;           // o*96 + i
        int i = oi % 96;
        int o = oi / 96;
        float acc = 0.f;
#pragma unroll
        for (int k = 0; k < 8; ++k)
            acc = fmaf(Wd[(size_t)j * 8 + k], u_s[i][k], acc);
        uh[o][i][d] = acc;
    }
    __syncthreads();
    const int o = t >> 4, d = t & 15;
    if (t < 32) {
        float s = 0.f;
        for (int i = 0; i < 96; ++i) s += 0.5f * uh[o][i][d];
        float n2 = s * s;
        n2 += __shfl_xor(n2, 1); n2 += __shfl_xor(n2, 2);
        n2 += __shfl_xor(n2, 4); n2 += __shfl_xor(n2, 8);
        float nr = sqrtf(n2);
        vv[o][d] = tanhf(nr) * s / (nr + 1e-8f);
    }
    __syncthreads();
    for (int j = t; j < 192; j += 64) {
        int oo = j / 96, ii = j - oo * 96;
        float bsum = 0.f;
#pragma unroll
        for (int dd = 0; dd < 16; ++dd)
            bsum = fmaf(uh[oo][ii][dd], vv[oo][dd], bsum);
        cc2[oo][ii] = bsum;
    }
    __syncthreads();
    for (int ii = t; ii < 96; ii += 64) {
        float b0 = cc2[0][ii], b1v = cc2[1][ii];
        float m = fmaxf(b0, b1v);
        float e0 = expf(b0 - m), e1 = expf(b1v - m);
        float inv = 1.f / (e0 + e1);
        cc2[0][ii] = e0 * inv;
        cc2[1][ii] = e1 * inv;
    }
    __syncthreads();
    if (t < 32) {
        float s = 0.f;
        for (int i = 0; i < 96; ++i) s = fmaf(cc2[o][i], uh[o][i][d], s);
        float n2 = s * s;
        n2 += __shfl_xor(n2, 1); n2 += __shfl_xor(n2, 2);
        n2 += __shfl_xor(n2, 4); n2 += __shfl_xor(n2, 8);
        float nr = sqrtf(n2);
        float v = tanhf(nr) * s / (nr + 1e-8f);
        float n2v = v * v;
        n2v += __shfl_xor(n2v, 1); n2v += __shfl_xor(n2v, 2);
        n2v += __shfl_xor(n2v, 4); n2v += __shfl_xor(n2v, 8);
        vv[o][d] = v;
        if (d == 0) {
            float lg = sqrtf(n2v);
            lg_s[o] = lg;
            logits_out[(size_t)(c0 + il) * 2 + o] = lg;
        }
    }
    __syncthreads();
    if (t < 32) {
        int ostar = (lg_s[1] > lg_s[0]) ? 1 : 0;
        hbuf[(size_t)il * 32 + t] = (o == ostar) ? vv[o][d] : 0.f;
    }
}

// ---------------- decoder FC: out = act(in @ W^T + b) ----------------
__global__ __launch_bounds__(256) void fc_kernel(
    const float* __restrict__ in, const float* __restrict__ W,
    const float* __restrict__ bias, float* __restrict__ out,
    int M, int N, int K, int act) {
    __shared__ float As[64][33];
    __shared__ float Bs[64][33];
    const int t = threadIdx.x;
    const int m0 = blockIdx.x * 64, n0 = blockIdx.y * 64;
    const int tn = t & 15, tm = t >> 4;
    float acc[4][4];
#pragma unroll
    for (int i = 0; i < 4; ++i)
#pragma unroll
        for (int j = 0; j < 4; ++j) acc[i][j] = 0.f;
    const int rr = t >> 2, c8 = (t & 3) * 8;
    for (int kc = 0; kc < K; kc += 32) {
        __syncthreads();
        const int mrow = m0 + rr;
#pragma unroll
        for (int q = 0; q < 8; ++q) {
            As[rr][c8 + q] = (mrow < M) ? in[(size_t)mrow * K + kc + c8 + q] : 0.f;
            Bs[rr][c8 + q] = W[(size_t)(n0 + rr) * K + kc + c8 + q];
        }
        __syncthreads();
#pragma unroll
        for (int k = 0; k < 32; ++k) {
            float av[4], bv[4];
#pragma unroll
            for (int i = 0; i < 4; ++i) av[i] = As[tm * 4 + i][k];
#pragma unroll
            for (int j = 0; j < 4; ++j) bv[j] = Bs[tn * 4 + j][k];
#pragma unroll
            for (int i = 0; i < 4; ++i)
#pragma unroll
                for (int j = 0; j < 4; ++j) acc[i][j] = fmaf(av[i], bv[j], acc[i][j]);
        }
    }
#pragma unroll
    for (int i = 0; i < 4; ++i) {
        int m = m0 + tm * 4 + i;
        if (m < M) {
#pragma unroll
            for (int j = 0; j < 4; ++j) {
                int nn = n0 + tn * 4 + j;
                float v = acc[i][j] + bias[nn];
                if (act == 0) v = fmaxf(v, 0.f);
                else v = 1.f / (1.f + expf(-v));
                out[(size_t)m * N + nn] = v;
            }
        }
    }
}

// ---------------- host ----------------
extern "C" void kernel_launch(void* const* d_in, const int* in_sizes, int n_in,
                              void* d_out, int out_size, void* d_ws, size_t ws_size,
                              hipStream_t stream) {
    const float* x    = (const float*)d_in[0];
    const float* w1   = (const float*)d_in[1];
    const float* b1   = (const float*)d_in[2];
    const float* pcw  = (const float*)d_in[3];
    const float* pcb  = (const float*)d_in[4];
    const float* Wd   = (const float*)d_in[5];
    const float* dw1  = (const float*)d_in[6];
    const float* db1  = (const float*)d_in[7];
    const float* dw2  = (const float*)d_in[8];
    const float* db2  = (const float*)d_in[9];
    const float* dw3  = (const float*)d_in[10];
    const float* db3  = (const float*)d_in[11];
    float* out = (float*)d_out;

    const int B = 2048;
    float* ws = (float*)d_ws;
    unsigned short* wf = (unsigned short*)ws;       // 2,654,208 u16 = 1,327,104 float slots
    float* pcwr = ws + 1327104;                     // 786,432 floats
    float* dyn  = pcwr + 64 * 256 * 48;

    const long long base_floats = 1327104LL + 786432LL;
    const long long per_img = 50176 + 768 + 32 + 512 + 1024;   // 52,512 floats/img
    long long avail = (long long)(ws_size / 4) - base_floats;
    int CH;
    if (avail < per_img) CH = 1;
    else CH = (int)(avail / per_img);
    if (CH > B) CH = B;

    reorder_wf_kernel<<<(324 * 8 * 64 * 8 + 255) / 256, 256, 0, stream>>>(w1, wf);
    reorder_pcw_kernel<<<(64 * 256 * 48 + 255) / 256, 256, 0, stream>>>(pcw, pcwr);

    float* c1o  = dyn;
    float* pco  = c1o  + (size_t)CH * 50176;
    float* hbuf = pco  + (size_t)CH * 768;
    float* h1   = hbuf + (size_t)CH * 32;
    float* h2   = h1   + (size_t)CH * 512;

    for (int c0 = 0; c0 < B; c0 += CH) {
        int n = B - c0; if (n > CH) n = CH;
        conv1_mfma_kernel<<<n * 2, 256, 0, stream>>>(x, wf, b1, c1o, c0);
        pc_kernel<<<n, 256, 0, stream>>>(c1o, pcwr, pcb, pco);
        caps_kernel<<<n, 64, 0, stream>>>(pco, Wd, out, hbuf, c0);
        fc_kernel<<<dim3((n + 63) / 64, 8),  256, 0, stream>>>(hbuf, dw1, db1, h1, n, 512, 32, 0);
        fc_kernel<<<dim3((n + 63) / 64, 16), 256, 0, stream>>>(h1,   dw2, db2, h2, n, 1024, 512, 0);
        fc_kernel<<<dim3((n + 63) / 64, 4),  256, 0, stream>>>(h2,   dw3, db3, out + 4096 + (size_t)c0 * 256, n, 256, 1024, 1);
    }
}

// Round 5
// 3823.386 us; speedup vs baseline: 5.9828x; 2.5523x over previous
//
#include <hip/hip_runtime.h>
#include <cstdint>
#include <cstddef>

typedef short short8 __attribute__((ext_vector_type(8)));
typedef short short4v __attribute__((ext_vector_type(4)));
typedef float f32x16 __attribute__((ext_vector_type(16)));
typedef float f32x4 __attribute__((ext_vector_type(4)));

__device__ inline unsigned short bf16_rne(float x) {
    unsigned u = __float_as_uint(x);
    unsigned r = u + 0x7FFFu + ((u >> 16) & 1u);
    return (unsigned short)(r >> 16);
}
__device__ inline float bf16_to_f(unsigned short h) {
    return __uint_as_float(((unsigned)h) << 16);
}

// ---------------- weight reorders ----------------
// conv1_w (256,64,9,9) -> MFMA-fragment-order split-bf16 planes (32x32x16):
// wf[(ksg*8 + nc)*1024 u16]: [0..511]=hi frag, [512..1023]=lo frag
// ksg = cc*81 + tap (cc = 16-ci chunk) ; ci = cc*16 + (l>>5)*8 + j ; co = nc*32 + (l&31)
__global__ void reorder_wf_kernel(const float* __restrict__ w, unsigned short* __restrict__ wf) {
    int idx = blockIdx.x * 256 + threadIdx.x;      // over 324*8*64*8 = 1,327,104
    if (idx >= 324 * 8 * 64 * 8) return;
    int j   = idx & 7;
    int l   = (idx >> 3) & 63;
    int nc  = (idx >> 9) & 7;
    int ksg = idx >> 12;                           // 0..323
    int cc  = ksg / 81;
    int tap = ksg - cc * 81;
    int ci  = cc * 16 + ((l >> 5) << 3) + j;
    int co  = nc * 32 + (l & 31);
    float v = w[(co * 64 + ci) * 81 + tap];
    unsigned short hi = bf16_rne(v);
    unsigned short lo = bf16_rne(v - bf16_to_f(hi));
    size_t base = ((size_t)(ksg * 8 + nc)) * 1024;
    wf[base + l * 8 + j]       = hi;
    wf[base + 512 + l * 8 + j] = lo;
}

// pc_w (48,256,8,8) -> MFMA-fragment-order split-bf16 (16x16x32):
// dims [cc=8][tap=64][ct=3][plane=2][l=64][j=8] u16 ; total 1,572,864 u16 = 3 MB
// co = ct*16 + (l&15) ; ci = cc*32 + (l>>4)*8 + j ; plane0=hi, plane1=lo
__global__ void reorder_pcwf_kernel(const float* __restrict__ w, unsigned short* __restrict__ wf) {
    int idx = blockIdx.x * 256 + threadIdx.x;      // over 1,572,864
    if (idx >= 1572864) return;
    int j     = idx & 7;
    int l     = (idx >> 3) & 63;
    int plane = (idx >> 9) & 1;
    int rest  = idx >> 10;
    int ct    = rest % 3;
    int rest2 = rest / 3;
    int tap   = rest2 & 63;
    int cc    = rest2 >> 6;
    int co = ct * 16 + (l & 15);
    int ci = cc * 32 + ((l >> 4) << 3) + j;
    float v = w[((size_t)co * 256 + ci) * 64 + tap];
    unsigned short hi = bf16_rne(v);
    unsigned short out = plane ? bf16_rne(v - bf16_to_f(hi)) : hi;
    wf[idx] = out;
}

// ---------------- conv1 via split-bf16 MFMA ----------------
// per image: M=196px (7 tiles of 32, padded), N=256co, K=5184 (4 ci-chunks x 81 taps x 16)
// block = 256 thr = 4 waves = 4 n-cols of 32 co ; grid = n_images * 2 (co halves)
// LDS: Xs[484][36] u16 static = 34,848 B : per spatial row [hi ci 0..15][lo ci 0..15][pad 4]
#define RS 36

__global__ __launch_bounds__(256, 2) void conv1_mfma_kernel(
    const float* __restrict__ x, const unsigned short* __restrict__ wf,
    const float* __restrict__ b1, float* __restrict__ c1o, int c0)
{
    __shared__ unsigned short Xs[484 * RS];
    const int t  = threadIdx.x;
    const int l  = t & 63;
    const int w  = t >> 6;            // wave 0..3
    const int il = blockIdx.x >> 1;
    const int nb = blockIdx.x & 1;
    const int bg = c0 + il;
    const int ncol = nb * 4 + w;
    const int lane31 = l & 31;
    const int kg = l >> 5;
    const int co = ncol * 32 + lane31;
    const float bias = b1[co];

    int am[7];
#pragma unroll
    for (int mt = 0; mt < 7; ++mt) {
        int p  = mt * 32 + lane31;
        int pp = (p < 196) ? p : 0;      // clamp pad rows into valid LDS
        int oh = pp / 14, ow = pp - oh * 14;
        am[mt] = (oh * 22 + ow) * RS + kg * 8;
    }
    const char* wfb = (const char*)wf;
    const int boff = ncol * 2048 + l * 16;

    f32x16 acc[7];
#pragma unroll
    for (int mt = 0; mt < 7; ++mt) acc[mt] = (f32x16)(0.f);

    for (int cc = 0; cc < 4; ++cc) {
        __syncthreads();
        // stage 16-ci chunk: fp32 -> hi/lo bf16 halves of each spatial row
        for (int i = t; i < 16 * 121; i += 256) {
            int ci = i / 121;
            int sq = i - ci * 121;
            const float4 v = *(const float4*)(x + ((size_t)bg * 64 + cc * 16 + ci) * 484 + sq * 4);
#pragma unroll
            for (int e = 0; e < 4; ++e) {
                float xv = ((const float*)&v)[e];
                unsigned short hi = bf16_rne(xv);
                unsigned short lo = bf16_rne(xv - bf16_to_f(hi));
                int s = sq * 4 + e;
                Xs[s * RS + ci]      = hi;
                Xs[s * RS + 16 + ci] = lo;
            }
        }
        __syncthreads();

        const int ksgb = cc * 81;
        short8 bh0 = *(const short8*)(wfb + (size_t)ksgb * 16384 + boff);
        short8 bl0 = *(const short8*)(wfb + (size_t)ksgb * 16384 + 1024 + boff);

        for (int tap = 0; tap < 81; ++tap) {
            // prefetch next tap's B frags (L2-resident)
            int kn = ksgb + tap + 1; if (kn > 323) kn = 323;
            short8 bh1 = *(const short8*)(wfb + (size_t)kn * 16384 + boff);
            short8 bl1 = *(const short8*)(wfb + (size_t)kn * 16384 + 1024 + boff);

            const int kh = tap / 9, kw = tap - kh * 9;
            const int toff = (kh * 22 + kw) * RS;
#pragma unroll
            for (int mt = 0; mt < 7; ++mt) {
                const int a = am[mt] + toff;
                short4v h0 = *(const short4v*)(Xs + a);
                short4v h1 = *(const short4v*)(Xs + a + 4);
                short4v q0 = *(const short4v*)(Xs + a + 16);
                short4v q1 = *(const short4v*)(Xs + a + 20);
                short8 Ah = __builtin_shufflevector(h0, h1, 0, 1, 2, 3, 4, 5, 6, 7);
                short8 Al = __builtin_shufflevector(q0, q1, 0, 1, 2, 3, 4, 5, 6, 7);
                acc[mt] = __builtin_amdgcn_mfma_f32_32x32x16_bf16(Ah, bh0, acc[mt], 0, 0, 0);
                acc[mt] = __builtin_amdgcn_mfma_f32_32x32x16_bf16(Ah, bl0, acc[mt], 0, 0, 0);
                acc[mt] = __builtin_amdgcn_mfma_f32_32x32x16_bf16(Al, bh0, acc[mt], 0, 0, 0);
                acc[mt] = __builtin_amdgcn_mfma_f32_32x32x16_bf16(Al, bl0, acc[mt], 0, 0, 0);
            }
            bh0 = bh1; bl0 = bl1;
        }
    }

    // epilogue: bias + relu, NHWC store (C/D: col=lane&31, row=(r&3)+8*(r>>2)+4*(lane>>5))
#pragma unroll
    for (int mt = 0; mt < 7; ++mt) {
#pragma unroll
        for (int r = 0; r < 16; ++r) {
            int p = mt * 32 + (r & 3) + ((r >> 2) << 3) + kg * 4;
            if (p < 196) {
                float v = acc[mt][r] + bias;
                c1o[((size_t)il * 196 + p) * 256 + co] = fmaxf(v, 0.f);
            }
        }
    }
}

// ---------------- primary caps conv via split-bf16 MFMA ----------------
// per image: M=16 (4x4 out pos), N=48 (3 tiles of 16), K=16384 (8 chunks x 64 taps x 32 ci)
// block = 1 image, 4 waves splitting taps (tap % 4 == w); 16x16x32 MFMA
// LDS: Xh/Xl [196][36] u16 = 2 x 14,112 B; reduction reuses Xh
#define PC_RS 36

__global__ __launch_bounds__(256, 2) void pc_mfma_kernel(
    const float* __restrict__ c1o, const unsigned short* __restrict__ pcwf,
    const float* __restrict__ pcb, float* __restrict__ pco)
{
    __shared__ unsigned short Xh[196 * PC_RS];
    __shared__ unsigned short Xl[196 * PC_RS];
    const int t  = threadIdx.x;
    const int l  = t & 63;
    const int w  = t >> 6;
    const int il = blockIdx.x;
    const int pos = l & 15;           // A row
    const int kg  = l >> 4;           // k-group 0..3
    const int oh = pos >> 2, ow = pos & 3;
    const char* wb = (const char*)pcwf;

    f32x4 acc0 = (f32x4)(0.f), acc1 = (f32x4)(0.f), acc2 = (f32x4)(0.f);

    for (int cc = 0; cc < 8; ++cc) {
        __syncthreads();
        // stage 32-ci chunk of the image: fp32 NHWC -> hi/lo bf16 planes
        for (int q = t; q < 1568; q += 256) {          // 196 px * 8 float4
            int p  = q >> 3;
            int c4 = (q & 7) << 2;
            const float4 v = *(const float4*)(c1o + ((size_t)il * 196 + p) * 256 + cc * 32 + c4);
            short4v hv, lv;
#pragma unroll
            for (int e = 0; e < 4; ++e) {
                float xv = ((const float*)&v)[e];
                unsigned short hi = bf16_rne(xv);
                hv[e] = (short)hi;
                lv[e] = (short)bf16_rne(xv - bf16_to_f(hi));
            }
            *(short4v*)(Xh + p * PC_RS + c4) = hv;
            *(short4v*)(Xl + p * PC_RS + c4) = lv;
        }
        __syncthreads();

        // B frags for first tap of this wave
        short8 Bh0[3], Bl0[3], Bh1[3], Bl1[3];
        {
            const char* bp = wb + ((size_t)(cc * 64 + w) * 6) * 1024 + l * 16;
#pragma unroll
            for (int ct = 0; ct < 3; ++ct) {
                Bh0[ct] = *(const short8*)(bp + ct * 2048);
                Bl0[ct] = *(const short8*)(bp + ct * 2048 + 1024);
            }
        }
        for (int tt = 0; tt < 16; ++tt) {
            const int tap = tt * 4 + w;
            // prefetch next tap's B frags
            const int tapn = (tt == 15) ? tap : (tap + 4);
            const char* bpn = wb + ((size_t)(cc * 64 + tapn) * 6) * 1024 + l * 16;
#pragma unroll
            for (int ct = 0; ct < 3; ++ct) {
                Bh1[ct] = *(const short8*)(bpn + ct * 2048);
                Bl1[ct] = *(const short8*)(bpn + ct * 2048 + 1024);
            }
            const int kh = tap >> 3, kw = tap & 7;
            const int pix = (2 * oh + kh) * 14 + (2 * ow + kw);
            const int a = pix * PC_RS + kg * 8;
            short4v h0 = *(const short4v*)(Xh + a);
            short4v h1 = *(const short4v*)(Xh + a + 4);
            short4v q0 = *(const short4v*)(Xl + a);
            short4v q1 = *(const short4v*)(Xl + a + 4);
            short8 Ah = __builtin_shufflevector(h0, h1, 0, 1, 2, 3, 4, 5, 6, 7);
            short8 Al = __builtin_shufflevector(q0, q1, 0, 1, 2, 3, 4, 5, 6, 7);

            acc0 = __builtin_amdgcn_mfma_f32_16x16x32_bf16(Ah, Bh0[0], acc0, 0, 0, 0);
            acc0 = __builtin_amdgcn_mfma_f32_16x16x32_bf16(Ah, Bl0[0], acc0, 0, 0, 0);
            acc0 = __builtin_amdgcn_mfma_f32_16x16x32_bf16(Al, Bh0[0], acc0, 0, 0, 0);
            acc0 = __builtin_amdgcn_mfma_f32_16x16x32_bf16(Al, Bl0[0], acc0, 0, 0, 0);
            acc1 = __builtin_amdgcn_mfma_f32_16x16x32_bf16(Ah, Bh0[1], acc1, 0, 0, 0);
            acc1 = __builtin_amdgcn_mfma_f32_16x16x32_bf16(Ah, Bl0[1], acc1, 0, 0, 0);
            acc1 = __builtin_amdgcn_mfma_f32_16x16x32_bf16(Al, Bh0[1], acc1, 0, 0, 0);
            acc1 = __builtin_amdgcn_mfma_f32_16x16x32_bf16(Al, Bl0[1], acc1, 0, 0, 0);
            acc2 = __builtin_amdgcn_mfma_f32_16x16x32_bf16(Ah, Bh0[2], acc2, 0, 0, 0);
            acc2 = __builtin_amdgcn_mfma_f32_16x16x32_bf16(Ah, Bl0[2], acc2, 0, 0, 0);
            acc2 = __builtin_amdgcn_mfma_f32_16x16x32_bf16(Al, Bh0[2], acc2, 0, 0, 0);
            acc2 = __builtin_amdgcn_mfma_f32_16x16x32_bf16(Al, Bl0[2], acc2, 0, 0, 0);
#pragma unroll
            for (int ct = 0; ct < 3; ++ct) { Bh0[ct] = Bh1[ct]; Bl0[ct] = Bl1[ct]; }
        }
    }

    // cross-wave reduce (taps were split) + bias + store
    __syncthreads();
    float* R = (float*)Xh;   // 4 waves * 3 tiles * 64 lanes * 4 regs = 12,288 f32? no: 3072 f32 = 12,288 B <= 14,112 B
#pragma unroll
    for (int ct = 0; ct < 3; ++ct) {
        f32x4 a = (ct == 0) ? acc0 : (ct == 1) ? acc1 : acc2;
#pragma unroll
        for (int r = 0; r < 4; ++r)
            R[(((w * 3 + ct) * 64) + l) * 4 + r] = a[r];
    }
    __syncthreads();
    for (int idx = t; idx < 768; idx += 256) {
        int pp = idx & 15, co = idx >> 4;
        int ct = co >> 4, col = co & 15;
        int lane = ((pp >> 2) << 4) | col, reg = pp & 3;
        float s = 0.f;
#pragma unroll
        for (int w4 = 0; w4 < 4; ++w4)
            s += R[(((w4 * 3 + ct) * 64) + lane) * 4 + reg];
        pco[(size_t)il * 768 + idx] = s + pcb[co];
    }
}

// ---------------- capsule squash + u_hat + routing + logits + mask ----------------
__global__ __launch_bounds__(64) void caps_kernel(
    const float* __restrict__ pco, const float* __restrict__ Wd,
    float* __restrict__ logits_out, float* __restrict__ hbuf, int c0) {
    __shared__ float u_s[96][8];
    __shared__ float uh[2][96][16];
    __shared__ float vv[2][16];
    __shared__ float cc2[2][96];
    __shared__ float lg_s[2];
    const int t = threadIdx.x;
    const int il = blockIdx.x;

    for (int cap = t; cap < 96; cap += 64) {
        float xr[8];
        float n2 = 0.f;
#pragma unroll
        for (int k = 0; k < 8; ++k) {
            xr[k] = pco[(size_t)il * 768 + cap * 8 + k];
            n2 = fmaf(xr[k], xr[k], n2);
        }
        float nr = sqrtf(n2);
        float sc = tanhf(nr) / (nr + 1e-8f);
#pragma unroll
        for (int k = 0; k < 8; ++k) u_s[cap][k] = xr[k] * sc;
    }
    __syncthreads();
    // u_hat[o][i][d] = sum_k Wd[o][i][d][k] * u[i][k]  (j = (o*96+i)*16 + d)
    for (int j = t; j < 3072; j += 64) {
        int d = j & 15;
        int oi = j >> 4;           // o*96 + i
        int i = oi % 96;
        int o = oi / 96;
        float acc = 0.f;
#pragma unroll
        for (int k = 0; k < 8; ++k)
            acc = fmaf(Wd[(size_t)j * 8 + k], u_s[i][k], acc);
        uh[o][i][d] = acc;
    }
    __syncthreads();
    const int o = t >> 4, d = t & 15;
    if (t < 32) {
        float s = 0.f;
        for (int i = 0; i < 96; ++i) s += 0.5f * uh[o][i][d];
        float n2 = s * s;
        n2 += __shfl_xor(n2, 1); n2 += __shfl_xor(n2, 2);
        n2 += __shfl_xor(n2, 4); n2 += __shfl_xor(n2, 8);
        float nr = sqrtf(n2);
        vv[o][d] = tanhf(nr) * s / (nr + 1e-8f);
    }
    __syncthreads();
    for (int j = t; j < 192; j += 64) {
        int oo = j / 96, ii = j - oo * 96;
        float bsum = 0.f;
#pragma unroll
        for (int dd = 0; dd < 16; ++dd)
            bsum = fmaf(uh[oo][ii][dd], vv[oo][dd], bsum);
        cc2[oo][ii] = bsum;
    }
    __syncthreads();
    for (int ii = t; ii < 96; ii += 64) {
        float b0 = cc2[0][ii], b1v = cc2[1][ii];
        float m = fmaxf(b0, b1v);
        float e0 = expf(b0 - m), e1 = expf(b1v - m);
        float inv = 1.f / (e0 + e1);
        cc2[0][ii] = e0 * inv;
        cc2[1][ii] = e1 * inv;
    }
    __syncthreads();
    if (t < 32) {
        float s = 0.f;
        for (int i = 0; i < 96; ++i) s = fmaf(cc2[o][i], uh[o][i][d], s);
        float n2 = s * s;
        n2 += __shfl_xor(n2, 1); n2 += __shfl_xor(n2, 2);
        n2 += __shfl_xor(n2, 4); n2 += __shfl_xor(n2, 8);
        float nr = sqrtf(n2);
        float v = tanhf(nr) * s / (nr + 1e-8f);
        float n2v = v * v;
        n2v += __shfl_xor(n2v, 1); n2v += __shfl_xor(n2v, 2);
        n2v += __shfl_xor(n2v, 4); n2v += __shfl_xor(n2v, 8);
        vv[o][d] = v;
        if (d == 0) {
            float lg = sqrtf(n2v);
            lg_s[o] = lg;
            logits_out[(size_t)(c0 + il) * 2 + o] = lg;
        }
    }
    __syncthreads();
    if (t < 32) {
        int ostar = (lg_s[1] > lg_s[0]) ? 1 : 0;
        hbuf[(size_t)il * 32 + t] = (o == ostar) ? vv[o][d] : 0.f;
    }
}

// ---------------- decoder FC: out = act(in @ W^T + b) ----------------
__global__ __launch_bounds__(256) void fc_kernel(
    const float* __restrict__ in, const float* __restrict__ W,
    const float* __restrict__ bias, float* __restrict__ out,
    int M, int N, int K, int act) {
    __shared__ float As[64][33];
    __shared__ float Bs[64][33];
    const int t = threadIdx.x;
    const int m0 = blockIdx.x * 64, n0 = blockIdx.y * 64;
    const int tn = t & 15, tm = t >> 4;
    float acc[4][4];
#pragma unroll
    for (int i = 0; i < 4; ++i)
#pragma unroll
        for (int j = 0; j < 4; ++j) acc[i][j] = 0.f;
    const int rr = t >> 2, c8 = (t & 3) * 8;
    for (int kc = 0; kc < K; kc += 32) {
        __syncthreads();
        const int mrow = m0 + rr;
#pragma unroll
        for (int q = 0; q < 8; ++q) {
            As[rr][c8 + q] = (mrow < M) ? in[(size_t)mrow * K + kc + c8 + q] : 0.f;
            Bs[rr][c8 + q] = W[(size_t)(n0 + rr) * K + kc + c8 + q];
        }
        __syncthreads();
#pragma unroll
        for (int k = 0; k < 32; ++k) {
            float av[4], bv[4];
#pragma unroll
            for (int i = 0; i < 4; ++i) av[i] = As[tm * 4 + i][k];
#pragma unroll
            for (int j = 0; j < 4; ++j) bv[j] = Bs[tn * 4 + j][k];
#pragma unroll
            for (int i = 0; i < 4; ++i)
#pragma unroll
                for (int j = 0; j < 4; ++j) acc[i][j] = fmaf(av[i], bv[j], acc[i][j]);
        }
    }
#pragma unroll
    for (int i = 0; i < 4; ++i) {
        int m = m0 + tm * 4 + i;
        if (m < M) {
#pragma unroll
            for (int j = 0; j < 4; ++j) {
                int nn = n0 + tn * 4 + j;
                float v = acc[i][j] + bias[nn];
                if (act == 0) v = fmaxf(v, 0.f);
                else v = 1.f / (1.f + expf(-v));
                out[(size_t)m * N + nn] = v;
            }
        }
    }
}

// ---------------- host ----------------
extern "C" void kernel_launch(void* const* d_in, const int* in_sizes, int n_in,
                              void* d_out, int out_size, void* d_ws, size_t ws_size,
                              hipStream_t stream) {
    const float* x    = (const float*)d_in[0];
    const float* w1   = (const float*)d_in[1];
    const float* b1   = (const float*)d_in[2];
    const float* pcw  = (const float*)d_in[3];
    const float* pcb  = (const float*)d_in[4];
    const float* Wd   = (const float*)d_in[5];
    const float* dw1  = (const float*)d_in[6];
    const float* db1  = (const float*)d_in[7];
    const float* dw2  = (const float*)d_in[8];
    const float* db2  = (const float*)d_in[9];
    const float* dw3  = (const float*)d_in[10];
    const float* db3  = (const float*)d_in[11];
    float* out = (float*)d_out;

    const int B = 2048;
    float* ws = (float*)d_ws;
    unsigned short* wf = (unsigned short*)ws;       // 2,654,208 u16 = 1,327,104 float slots
    unsigned short* pcwf = (unsigned short*)(ws + 1327104);  // 1,572,864 u16 = 786,432 float slots
    float* dyn  = ws + 1327104 + 786432;

    const long long base_floats = 1327104LL + 786432LL;
    const long long per_img = 50176 + 768 + 32 + 512 + 1024;   // 52,512 floats/img
    long long avail = (long long)(ws_size / 4) - base_floats;
    int CH;
    if (avail < per_img) CH = 1;
    else CH = (int)(avail / per_img);
    if (CH > B) CH = B;

    reorder_wf_kernel<<<(324 * 8 * 64 * 8 + 255) / 256, 256, 0, stream>>>(w1, wf);
    reorder_pcwf_kernel<<<(1572864 + 255) / 256, 256, 0, stream>>>(pcw, pcwf);

    float* c1o  = dyn;
    float* pco  = c1o  + (size_t)CH * 50176;
    float* hbuf = pco  + (size_t)CH * 768;
    float* h1   = hbuf + (size_t)CH * 32;
    float* h2   = h1   + (size_t)CH * 512;

    for (int c0 = 0; c0 < B; c0 += CH) {
        int n = B - c0; if (n > CH) n = CH;
        conv1_mfma_kernel<<<n * 2, 256, 0, stream>>>(x, wf, b1, c1o, c0);
        pc_mfma_kernel<<<n, 256, 0, stream>>>(c1o, pcwf, pcb, pco);
        caps_kernel<<<n, 64, 0, stream>>>(pco, Wd, out, hbuf, c0);
        fc_kernel<<<dim3((n + 63) / 64, 8),  256, 0, stream>>>(hbuf, dw1, db1, h1, n, 512, 32, 0);
        fc_kernel<<<dim3((n + 63) / 64, 16), 256, 0, stream>>>(h1,   dw2, db2, h2, n, 1024, 512, 0);
        fc_kernel<<<dim3((n + 63) / 64, 4),  256, 0, stream>>>(h2,   dw3, db3, out + 4096 + (size_t)c0 * 256, n, 256, 1024, 1);
    }
}

// Round 6
// 3807.107 us; speedup vs baseline: 6.0084x; 1.0043x over previous
//
#include <hip/hip_runtime.h>
#include <cstdint>
#include <cstddef>

typedef short short8 __attribute__((ext_vector_type(8)));
typedef short short4v __attribute__((ext_vector_type(4)));
typedef float f32x16 __attribute__((ext_vector_type(16)));
typedef float f32x4 __attribute__((ext_vector_type(4)));

__device__ inline unsigned short bf16_rne(float x) {
    unsigned u = __float_as_uint(x);
    unsigned r = u + 0x7FFFu + ((u >> 16) & 1u);
    return (unsigned short)(r >> 16);
}
__device__ inline float bf16_to_f(unsigned short h) {
    return __uint_as_float(((unsigned)h) << 16);
}

// ---------------- weight reorders ----------------
// conv1_w (256,64,9,9) -> MFMA-fragment-order split-bf16 planes (32x32x16):
// wf[(ksg*8 + nc)*1024 u16]: [0..511]=hi frag, [512..1023]=lo frag
// ksg = cc*81 + tap (cc = 16-ci chunk) ; ci = cc*16 + (l>>5)*8 + j ; co = nc*32 + (l&31)
__global__ void reorder_wf_kernel(const float* __restrict__ w, unsigned short* __restrict__ wf) {
    int idx = blockIdx.x * 256 + threadIdx.x;      // over 324*8*64*8 = 1,327,104
    if (idx >= 324 * 8 * 64 * 8) return;
    int j   = idx & 7;
    int l   = (idx >> 3) & 63;
    int nc  = (idx >> 9) & 7;
    int ksg = idx >> 12;                           // 0..323
    int cc  = ksg / 81;
    int tap = ksg - cc * 81;
    int ci  = cc * 16 + ((l >> 5) << 3) + j;
    int co  = nc * 32 + (l & 31);
    float v = w[(co * 64 + ci) * 81 + tap];
    unsigned short hi = bf16_rne(v);
    unsigned short lo = bf16_rne(v - bf16_to_f(hi));
    size_t base = ((size_t)(ksg * 8 + nc)) * 1024;
    wf[base + l * 8 + j]       = hi;
    wf[base + 512 + l * 8 + j] = lo;
}

// pc_w (48,256,8,8) -> MFMA-fragment-order split-bf16 (16x16x32):
// dims [cc=8][tap=64][ct=3][plane=2][l=64][j=8] u16
__global__ void reorder_pcwf_kernel(const float* __restrict__ w, unsigned short* __restrict__ wf) {
    int idx = blockIdx.x * 256 + threadIdx.x;      // over 1,572,864
    if (idx >= 1572864) return;
    int j     = idx & 7;
    int l     = (idx >> 3) & 63;
    int plane = (idx >> 9) & 1;
    int rest  = idx >> 10;
    int ct    = rest % 3;
    int rest2 = rest / 3;
    int tap   = rest2 & 63;
    int cc    = rest2 >> 6;
    int co = ct * 16 + (l & 15);
    int ci = cc * 32 + ((l >> 4) << 3) + j;
    float v = w[((size_t)co * 256 + ci) * 64 + tap];
    unsigned short hi = bf16_rne(v);
    unsigned short out = plane ? bf16_rne(v - bf16_to_f(hi)) : hi;
    wf[idx] = out;
}

// ---------------- conv1 via split-bf16 MFMA ----------------
// per image: M=196px (7 tiles of 32, padded), N=256co, K=5184 (4 ci-chunks x 81 taps x 16)
// block = 512 thr = 8 waves = 8 n-cols of 32 co ; grid = n images
// LDS: Xs[484][40] u16 = 38,720 B : per row [hi ci0-15][lo ci0-15][pad 8] -> 16B-aligned b128 frags
#define RS 40

__global__ __launch_bounds__(512, 1) void conv1_mfma_kernel(
    const float* __restrict__ x, const unsigned short* __restrict__ wf,
    const float* __restrict__ b1, float* __restrict__ c1o, int c0)
{
    __shared__ __align__(16) unsigned short Xs[484 * RS];
    const int t  = threadIdx.x;
    const int l  = t & 63;
    const int w  = t >> 6;            // wave = ncol 0..7
    const int il = blockIdx.x;
    const int bg = c0 + il;
    const int lane31 = l & 31;
    const int kg = l >> 5;
    const int co = w * 32 + lane31;
    const float bias = b1[co];

    int am[7];
#pragma unroll
    for (int mt = 0; mt < 7; ++mt) {
        int p  = mt * 32 + lane31;
        int pp = (p < 196) ? p : 0;      // clamp pad rows into valid LDS
        int oh = pp / 14, ow = pp - oh * 14;
        am[mt] = (oh * 22 + ow) * RS + kg * 8;
    }
    const char* wfb = (const char*)wf;
    const int boff = w * 2048 + l * 16;

    const int sidx = t >> 2;          // staging pixel row for rounds (+128/round)
    const int sblk = t & 3;           // staging ci block (4 ci)

    f32x16 acc[7];
#pragma unroll
    for (int mt = 0; mt < 7; ++mt) acc[mt] = (f32x16)(0.f);

    // prologue: stage cc=0 (gather-transpose, vector LDS writes)
#pragma unroll
    for (int r = 0; r < 4; ++r) {
        int s = sidx + r * 128;
        if (s < 484) {
            short4v hv, lv;
#pragma unroll
            for (int e = 0; e < 4; ++e) {
                float xv = x[((size_t)bg * 64 + sblk * 4 + e) * 484 + s];
                unsigned short hi = bf16_rne(xv);
                hv[e] = (short)hi;
                lv[e] = (short)bf16_rne(xv - bf16_to_f(hi));
            }
            *(short4v*)(Xs + s * RS + sblk * 4)      = hv;
            *(short4v*)(Xs + s * RS + 16 + sblk * 4) = lv;
        }
    }
    __syncthreads();

    for (int cc = 0; cc < 4; ++cc) {
        // issue next chunk's global loads early; latency hides under the 81 taps
        float vx[4][4];
        if (cc < 3) {
#pragma unroll
            for (int r = 0; r < 4; ++r) {
                int s = sidx + r * 128;
                if (s < 484) {
#pragma unroll
                    for (int e = 0; e < 4; ++e)
                        vx[r][e] = x[((size_t)bg * 64 + (cc + 1) * 16 + sblk * 4 + e) * 484 + s];
                }
            }
        }

        const int ksgb = cc * 81;
        short8 bh0 = *(const short8*)(wfb + (size_t)ksgb * 16384 + boff);
        short8 bl0 = *(const short8*)(wfb + (size_t)ksgb * 16384 + 1024 + boff);

        for (int tap = 0; tap < 81; ++tap) {
            // prefetch next tap's B frags (L2-resident)
            int kn = ksgb + tap + 1; if (kn > 323) kn = 323;
            short8 bh1 = *(const short8*)(wfb + (size_t)kn * 16384 + boff);
            short8 bl1 = *(const short8*)(wfb + (size_t)kn * 16384 + 1024 + boff);

            const int kh = tap / 9, kw = tap - kh * 9;
            const int toff = (kh * 22 + kw) * RS;
#pragma unroll
            for (int mt = 0; mt < 7; ++mt) {
                const int a = am[mt] + toff;
                short8 Ah = *(const short8*)(Xs + a);
                short8 Al = *(const short8*)(Xs + a + 16);
                acc[mt] = __builtin_amdgcn_mfma_f32_32x32x16_bf16(Ah, bh0, acc[mt], 0, 0, 0);
                acc[mt] = __builtin_amdgcn_mfma_f32_32x32x16_bf16(Ah, bl0, acc[mt], 0, 0, 0);
                acc[mt] = __builtin_amdgcn_mfma_f32_32x32x16_bf16(Al, bh0, acc[mt], 0, 0, 0);
                acc[mt] = __builtin_amdgcn_mfma_f32_32x32x16_bf16(Al, bl0, acc[mt], 0, 0, 0);
            }
            bh0 = bh1; bl0 = bl1;
        }

        if (cc < 3) {
            __syncthreads();          // all waves done reading Xs for this cc
#pragma unroll
            for (int r = 0; r < 4; ++r) {
                int s = sidx + r * 128;
                if (s < 484) {
                    short4v hv, lv;
#pragma unroll
                    for (int e = 0; e < 4; ++e) {
                        float xv = vx[r][e];
                        unsigned short hi = bf16_rne(xv);
                        hv[e] = (short)hi;
                        lv[e] = (short)bf16_rne(xv - bf16_to_f(hi));
                    }
                    *(short4v*)(Xs + s * RS + sblk * 4)      = hv;
                    *(short4v*)(Xs + s * RS + 16 + sblk * 4) = lv;
                }
            }
            __syncthreads();
        }
    }

    // epilogue: bias + relu, NHWC store (C/D: col=lane&31, row=(r&3)+8*(r>>2)+4*(lane>>5))
#pragma unroll
    for (int mt = 0; mt < 7; ++mt) {
#pragma unroll
        for (int r = 0; r < 16; ++r) {
            int p = mt * 32 + (r & 3) + ((r >> 2) << 3) + kg * 4;
            if (p < 196) {
                float v = acc[mt][r] + bias;
                c1o[((size_t)il * 196 + p) * 256 + co] = fmaxf(v, 0.f);
            }
        }
    }
}

// ---------------- primary caps conv via split-bf16 MFMA ----------------
#define PC_RS 36

__global__ __launch_bounds__(256, 2) void pc_mfma_kernel(
    const float* __restrict__ c1o, const unsigned short* __restrict__ pcwf,
    const float* __restrict__ pcb, float* __restrict__ pco)
{
    __shared__ unsigned short Xh[196 * PC_RS];
    __shared__ unsigned short Xl[196 * PC_RS];
    const int t  = threadIdx.x;
    const int l  = t & 63;
    const int w  = t >> 6;
    const int il = blockIdx.x;
    const int pos = l & 15;           // A row
    const int kg  = l >> 4;           // k-group 0..3
    const int oh = pos >> 2, ow = pos & 3;
    const char* wb = (const char*)pcwf;

    f32x4 acc0 = (f32x4)(0.f), acc1 = (f32x4)(0.f), acc2 = (f32x4)(0.f);

    for (int cc = 0; cc < 8; ++cc) {
        __syncthreads();
        for (int q = t; q < 1568; q += 256) {          // 196 px * 8 float4
            int p  = q >> 3;
            int c4 = (q & 7) << 2;
            const float4 v = *(const float4*)(c1o + ((size_t)il * 196 + p) * 256 + cc * 32 + c4);
            short4v hv, lv;
#pragma unroll
            for (int e = 0; e < 4; ++e) {
                float xv = ((const float*)&v)[e];
                unsigned short hi = bf16_rne(xv);
                hv[e] = (short)hi;
                lv[e] = (short)bf16_rne(xv - bf16_to_f(hi));
            }
            *(short4v*)(Xh + p * PC_RS + c4) = hv;
            *(short4v*)(Xl + p * PC_RS + c4) = lv;
        }
        __syncthreads();

        short8 Bh0[3], Bl0[3], Bh1[3], Bl1[3];
        {
            const char* bp = wb + ((size_t)(cc * 64 + w) * 6) * 1024 + l * 16;
#pragma unroll
            for (int ct = 0; ct < 3; ++ct) {
                Bh0[ct] = *(const short8*)(bp + ct * 2048);
                Bl0[ct] = *(const short8*)(bp + ct * 2048 + 1024);
            }
        }
        for (int tt = 0; tt < 16; ++tt) {
            const int tap = tt * 4 + w;
            const int tapn = (tt == 15) ? tap : (tap + 4);
            const char* bpn = wb + ((size_t)(cc * 64 + tapn) * 6) * 1024 + l * 16;
#pragma unroll
            for (int ct = 0; ct < 3; ++ct) {
                Bh1[ct] = *(const short8*)(bpn + ct * 2048);
                Bl1[ct] = *(const short8*)(bpn + ct * 2048 + 1024);
            }
            const int kh = tap >> 3, kw = tap & 7;
            const int pix = (2 * oh + kh) * 14 + (2 * ow + kw);
            const int a = pix * PC_RS + kg * 8;
            short4v h0 = *(const short4v*)(Xh + a);
            short4v h1 = *(const short4v*)(Xh + a + 4);
            short4v q0 = *(const short4v*)(Xl + a);
            short4v q1 = *(const short4v*)(Xl + a + 4);
            short8 Ah = __builtin_shufflevector(h0, h1, 0, 1, 2, 3, 4, 5, 6, 7);
            short8 Al = __builtin_shufflevector(q0, q1, 0, 1, 2, 3, 4, 5, 6, 7);

            acc0 = __builtin_amdgcn_mfma_f32_16x16x32_bf16(Ah, Bh0[0], acc0, 0, 0, 0);
            acc0 = __builtin_amdgcn_mfma_f32_16x16x32_bf16(Ah, Bl0[0], acc0, 0, 0, 0);
            acc0 = __builtin_amdgcn_mfma_f32_16x16x32_bf16(Al, Bh0[0], acc0, 0, 0, 0);
            acc0 = __builtin_amdgcn_mfma_f32_16x16x32_bf16(Al, Bl0[0], acc0, 0, 0, 0);
            acc1 = __builtin_amdgcn_mfma_f32_16x16x32_bf16(Ah, Bh0[1], acc1, 0, 0, 0);
            acc1 = __builtin_amdgcn_mfma_f32_16x16x32_bf16(Ah, Bl0[1], acc1, 0, 0, 0);
            acc1 = __builtin_amdgcn_mfma_f32_16x16x32_bf16(Al, Bh0[1], acc1, 0, 0, 0);
            acc1 = __builtin_amdgcn_mfma_f32_16x16x32_bf16(Al, Bl0[1], acc1, 0, 0, 0);
            acc2 = __builtin_amdgcn_mfma_f32_16x16x32_bf16(Ah, Bh0[2], acc2, 0, 0, 0);
            acc2 = __builtin_amdgcn_mfma_f32_16x16x32_bf16(Ah, Bl0[2], acc2, 0, 0, 0);
            acc2 = __builtin_amdgcn_mfma_f32_16x16x32_bf16(Al, Bh0[2], acc2, 0, 0, 0);
            acc2 = __builtin_amdgcn_mfma_f32_16x16x32_bf16(Al, Bl0[2], acc2, 0, 0, 0);
#pragma unroll
            for (int ct = 0; ct < 3; ++ct) { Bh0[ct] = Bh1[ct]; Bl0[ct] = Bl1[ct]; }
        }
    }

    __syncthreads();
    float* R = (float*)Xh;
#pragma unroll
    for (int ct = 0; ct < 3; ++ct) {
        f32x4 a = (ct == 0) ? acc0 : (ct == 1) ? acc1 : acc2;
#pragma unroll
        for (int r = 0; r < 4; ++r)
            R[(((w * 3 + ct) * 64) + l) * 4 + r] = a[r];
    }
    __syncthreads();
    for (int idx = t; idx < 768; idx += 256) {
        int pp = idx & 15, co = idx >> 4;
        int ct = co >> 4, col = co & 15;
        int lane = ((pp >> 2) << 4) | col, reg = pp & 3;
        float s = 0.f;
#pragma unroll
        for (int w4 = 0; w4 < 4; ++w4)
            s += R[(((w4 * 3 + ct) * 64) + lane) * 4 + reg];
        pco[(size_t)il * 768 + idx] = s + pcb[co];
    }
}

// ---------------- capsule squash + u_hat + routing + logits + mask ----------------
__global__ __launch_bounds__(64) void caps_kernel(
    const float* __restrict__ pco, const float* __restrict__ Wd,
    float* __restrict__ logits_out, float* __restrict__ hbuf, int c0) {
    __shared__ float u_s[96][8];
    __shared__ float uh[2][96][16];
    __shared__ float vv[2][16];
    __shared__ float cc2[2][96];
    __shared__ float lg_s[2];
    const int t = threadIdx.x;
    const int il = blockIdx.x;

    for (int cap = t; cap < 96; cap += 64) {
        float xr[8];
        float n2 = 0.f;
#pragma unroll
        for (int k = 0; k < 8; ++k) {
            xr[k] = pco[(size_t)il * 768 + cap * 8 + k];
            n2 = fmaf(xr[k], xr[k], n2);
        }
        float nr = sqrtf(n2);
        float sc = tanhf(nr) / (nr + 1e-8f);
#pragma unroll
        for (int k = 0; k < 8; ++k) u_s[cap][k] = xr[k] * sc;
    }
    __syncthreads();
    for (int j = t; j < 3072; j += 64) {
        int d = j & 15;
        int oi = j >> 4;           // o*96 + i
        int i = oi % 96;
        int o = oi / 96;
        float acc = 0.f;
#pragma unroll
        for (int k = 0; k < 8; ++k)
            acc = fmaf(Wd[(size_t)j * 8 + k], u_s[i][k], acc);
        uh[o][i][d] = acc;
    }
    __syncthreads();
    const int o = t >> 4, d = t & 15;
    if (t < 32) {
        float s = 0.f;
        for (int i = 0; i < 96; ++i) s += 0.5f * uh[o][i][d];
        float n2 = s * s;
        n2 += __shfl_xor(n2, 1); n2 += __shfl_xor(n2, 2);
        n2 += __shfl_xor(n2, 4); n2 += __shfl_xor(n2, 8);
        float nr = sqrtf(n2);
        vv[o][d] = tanhf(nr) * s / (nr + 1e-8f);
    }
    __syncthreads();
    for (int j = t; j < 192; j += 64) {
        int oo = j / 96, ii = j - oo * 96;
        float bsum = 0.f;
#pragma unroll
        for (int dd = 0; dd < 16; ++dd)
            bsum = fmaf(uh[oo][ii][dd], vv[oo][dd], bsum);
        cc2[oo][ii] = bsum;
    }
    __syncthreads();
    for (int ii = t; ii < 96; ii += 64) {
        float b0 = cc2[0][ii], b1v = cc2[1][ii];
        float m = fmaxf(b0, b1v);
        float e0 = expf(b0 - m), e1 = expf(b1v - m);
        float inv = 1.f / (e0 + e1);
        cc2[0][ii] = e0 * inv;
        cc2[1][ii] = e1 * inv;
    }
    __syncthreads();
    if (t < 32) {
        float s = 0.f;
        for (int i = 0; i < 96; ++i) s = fmaf(cc2[o][i], uh[o][i][d], s);
        float n2 = s * s;
        n2 += __shfl_xor(n2, 1); n2 += __shfl_xor(n2, 2);
        n2 += __shfl_xor(n2, 4); n2 += __shfl_xor(n2, 8);
        float nr = sqrtf(n2);
        float v = tanhf(nr) * s / (nr + 1e-8f);
        float n2v = v * v;
        n2v += __shfl_xor(n2v, 1); n2v += __shfl_xor(n2v, 2);
        n2v += __shfl_xor(n2v, 4); n2v += __shfl_xor(n2v, 8);
        vv[o][d] = v;
        if (d == 0) {
            float lg = sqrtf(n2v);
            lg_s[o] = lg;
            logits_out[(size_t)(c0 + il) * 2 + o] = lg;
        }
    }
    __syncthreads();
    if (t < 32) {
        int ostar = (lg_s[1] > lg_s[0]) ? 1 : 0;
        hbuf[(size_t)il * 32 + t] = (o == ostar) ? vv[o][d] : 0.f;
    }
}

// ---------------- decoder FC: out = act(in @ W^T + b) ----------------
__global__ __launch_bounds__(256) void fc_kernel(
    const float* __restrict__ in, const float* __restrict__ W,
    const float* __restrict__ bias, float* __restrict__ out,
    int M, int N, int K, int act) {
    __shared__ float As[64][33];
    __shared__ float Bs[64][33];
    const int t = threadIdx.x;
    const int m0 = blockIdx.x * 64, n0 = blockIdx.y * 64;
    const int tn = t & 15, tm = t >> 4;
    float acc[4][4];
#pragma unroll
    for (int i = 0; i < 4; ++i)
#pragma unroll
        for (int j = 0; j < 4; ++j) acc[i][j] = 0.f;
    const int rr = t >> 2, c8 = (t & 3) * 8;
    for (int kc = 0; kc < K; kc += 32) {
        __syncthreads();
        const int mrow = m0 + rr;
#pragma unroll
        for (int q = 0; q < 8; ++q) {
            As[rr][c8 + q] = (mrow < M) ? in[(size_t)mrow * K + kc + c8 + q] : 0.f;
            Bs[rr][c8 + q] = W[(size_t)(n0 + rr) * K + kc + c8 + q];
        }
        __syncthreads();
#pragma unroll
        for (int k = 0; k < 32; ++k) {
            float av[4], bv[4];
#pragma unroll
            for (int i = 0; i < 4; ++i) av[i] = As[tm * 4 + i][k];
#pragma unroll
            for (int j = 0; j < 4; ++j) bv[j] = Bs[tn * 4 + j][k];
#pragma unroll
            for (int i = 0; i < 4; ++i)
#pragma unroll
                for (int j = 0; j < 4; ++j) acc[i][j] = fmaf(av[i], bv[j], acc[i][j]);
        }
    }
#pragma unroll
    for (int i = 0; i < 4; ++i) {
        int m = m0 + tm * 4 + i;
        if (m < M) {
#pragma unroll
            for (int j = 0; j < 4; ++j) {
                int nn = n0 + tn * 4 + j;
                float v = acc[i][j] + bias[nn];
                if (act == 0) v = fmaxf(v, 0.f);
                else v = 1.f / (1.f + expf(-v));
                out[(size_t)m * N + nn] = v;
            }
        }
    }
}

// ---------------- host ----------------
extern "C" void kernel_launch(void* const* d_in, const int* in_sizes, int n_in,
                              void* d_out, int out_size, void* d_ws, size_t ws_size,
                              hipStream_t stream) {
    const float* x    = (const float*)d_in[0];
    const float* w1   = (const float*)d_in[1];
    const float* b1   = (const float*)d_in[2];
    const float* pcw  = (const float*)d_in[3];
    const float* pcb  = (const float*)d_in[4];
    const float* Wd   = (const float*)d_in[5];
    const float* dw1  = (const float*)d_in[6];
    const float* db1  = (const float*)d_in[7];
    const float* dw2  = (const float*)d_in[8];
    const float* db2  = (const float*)d_in[9];
    const float* dw3  = (const float*)d_in[10];
    const float* db3  = (const float*)d_in[11];
    float* out = (float*)d_out;

    const int B = 2048;
    float* ws = (float*)d_ws;
    unsigned short* wf = (unsigned short*)ws;                // 2,654,208 u16
    unsigned short* pcwf = (unsigned short*)(ws + 1327104);  // 1,572,864 u16
    float* dyn  = ws + 1327104 + 786432;

    const long long base_floats = 1327104LL + 786432LL;
    const long long per_img = 50176 + 768 + 32 + 512 + 1024;   // 52,512 floats/img
    long long avail = (long long)(ws_size / 4) - base_floats;
    int CH;
    if (avail < per_img) CH = 1;
    else CH = (int)(avail / per_img);
    if (CH > B) CH = B;

    reorder_wf_kernel<<<(324 * 8 * 64 * 8 + 255) / 256, 256, 0, stream>>>(w1, wf);
    reorder_pcwf_kernel<<<(1572864 + 255) / 256, 256, 0, stream>>>(pcw, pcwf);

    float* c1o  = dyn;
    float* pco  = c1o  + (size_t)CH * 50176;
    float* hbuf = pco  + (size_t)CH * 768;
    float* h1   = hbuf + (size_t)CH * 32;
    float* h2   = h1   + (size_t)CH * 512;

    for (int c0 = 0; c0 < B; c0 += CH) {
        int n = B - c0; if (n > CH) n = CH;
        conv1_mfma_kernel<<<n, 512, 0, stream>>>(x, wf, b1, c1o, c0);
        pc_mfma_kernel<<<n, 256, 0, stream>>>(c1o, pcwf, pcb, pco);
        caps_kernel<<<n, 64, 0, stream>>>(pco, Wd, out, hbuf, c0);
        fc_kernel<<<dim3((n + 63) / 64, 8),  256, 0, stream>>>(hbuf, dw1, db1, h1, n, 512, 32, 0);
        fc_kernel<<<dim3((n + 63) / 64, 16), 256, 0, stream>>>(h1,   dw2, db2, h2, n, 1024, 512, 0);
        fc_kernel<<<dim3((n + 63) / 64, 4),  256, 0, stream>>>(h2,   dw3, db3, out + 4096 + (size_t)c0 * 256, n, 256, 1024, 1);
    }
}